// Round 12
// baseline (239.528 us; speedup 1.0000x reference)
//
#include <hip/hip_runtime.h>
#include <hip/hip_bf16.h>

#define N_NODES 50000
#define N_EDGES 800000
#define EMB 64
#define HID 64
#define N_CLASSES 10
#define N_GRAPHS 512

#define BKT_SHIFT 5
#define BKT_NODES 32
#define NB_BKT ((N_NODES + BKT_NODES - 1) / BKT_NODES)   // 1563
#define BKT_CAP 800      // mean 512 + ~12.7 sigma
#define EB_CHUNK 8192
#define EB_BLOCKS ((N_EDGES + EB_CHUNK - 1) / EB_CHUNK)  // 98
#define XFORM_BLOCKS NB_BKT                              // tile = bucket = 32 nodes
#define XPAD 68
#define POOL_SPAN 6

// bf16 row accumulate: 8 bf16 dims (uint4) into fp32[8]
#define ACC8(vv, A)                                                            \
    do {                                                                       \
        A[0] += __uint_as_float((vv).x << 16);                                 \
        A[1] += __uint_as_float((vv).x & 0xFFFF0000u);                         \
        A[2] += __uint_as_float((vv).y << 16);                                 \
        A[3] += __uint_as_float((vv).y & 0xFFFF0000u);                         \
        A[4] += __uint_as_float((vv).z << 16);                                 \
        A[5] += __uint_as_float((vv).z & 0xFFFF0000u);                         \
        A[6] += __uint_as_float((vv).w << 16);                                 \
        A[7] += __uint_as_float((vv).w & 0xFFFF0000u);                         \
    } while (0)

// Build this bucket's CSR in LDS from its ebuf region. All 256 threads.
__device__ __forceinline__ void build_local_csr(
    int bucket, const int* __restrict__ cnt, const int* __restrict__ ebuf,
    unsigned short* lcsr, int* nhist, int* sval, int* sexcl, int* ncur) {
    int tid = threadIdx.x;
    int bs = bucket * BKT_CAP;
    int ne = min(cnt[bucket], BKT_CAP);   // defensive clamp
    if (tid < BKT_NODES) { nhist[tid] = 0; ncur[tid] = 0; }
    __syncthreads();
    for (int i = tid; i < ne; i += 256)
        atomicAdd(&nhist[ebuf[bs + i] >> 16], 1);
    __syncthreads();
    if (tid < BKT_NODES) sval[tid] = nhist[tid];
    __syncthreads();
    for (int off = 1; off < BKT_NODES; off <<= 1) {
        int t = 0;
        if (tid < BKT_NODES && tid >= off) t = nhist[tid - off];
        __syncthreads();
        if (tid < BKT_NODES) nhist[tid] += t;
        __syncthreads();
    }
    if (tid < BKT_NODES) sexcl[tid] = nhist[tid] - sval[tid];
    __syncthreads();
    for (int i = tid; i < ne; i += 256) {
        int p = ebuf[bs + i];
        int l = p >> 16;
        int r = atomicAdd(&ncur[l], 1);
        lcsr[sexcl[l] + r] = (unsigned short)(p & 0xFFFF);
    }
    __syncthreads();
}

// mean over neighbors (indices in LDS lcsr[s0..s0+deg)) for lane slot sl.
__device__ __forceinline__ void agg_node8(
    int s0, int deg, int sl,
    const unsigned short* lcsr,
    const __hip_bfloat16* __restrict__ Pb,
    float out[8]) {
    float a[4][8];
#pragma unroll
    for (int i = 0; i < 4; i++)
#pragma unroll
        for (int j = 0; j < 8; j++) a[i][j] = 0.f;
    int s1 = s0 + deg;
    for (int base = s0; base < s1; base += 8) {
        int c = min(8, s1 - base);
        if (c == 8) {
            int n0 = lcsr[base + 0];
            int n1 = lcsr[base + 1];
            int n2 = lcsr[base + 2];
            int n3 = lcsr[base + 3];
            int n4 = lcsr[base + 4];
            int n5 = lcsr[base + 5];
            int n6 = lcsr[base + 6];
            int n7 = lcsr[base + 7];
            uint4 v0 = ((const uint4*)(Pb + (size_t)n0 * 64))[sl];
            uint4 v1 = ((const uint4*)(Pb + (size_t)n1 * 64))[sl];
            uint4 v2 = ((const uint4*)(Pb + (size_t)n2 * 64))[sl];
            uint4 v3 = ((const uint4*)(Pb + (size_t)n3 * 64))[sl];
            uint4 v4 = ((const uint4*)(Pb + (size_t)n4 * 64))[sl];
            uint4 v5 = ((const uint4*)(Pb + (size_t)n5 * 64))[sl];
            uint4 v6 = ((const uint4*)(Pb + (size_t)n6 * 64))[sl];
            uint4 v7 = ((const uint4*)(Pb + (size_t)n7 * 64))[sl];
            ACC8(v0, a[0]); ACC8(v1, a[1]); ACC8(v2, a[2]); ACC8(v3, a[3]);
            ACC8(v4, a[0]); ACC8(v5, a[1]); ACC8(v6, a[2]); ACC8(v7, a[3]);
        } else {
            for (int j = 0; j < c; j++) {
                int n = lcsr[base + j];
                uint4 v = ((const uint4*)(Pb + (size_t)n * 64))[sl];
                ACC8(v, a[j & 3]);
            }
        }
    }
    float inv = (deg > 0) ? 1.0f / (float)deg : 0.0f;
#pragma unroll
    for (int j = 0; j < 8; j++)
        out[j] = (a[0][j] + a[1][j] + a[2][j] + a[3][j]) * inv;
}

// 32-node-tile GEMM: out_l = X@Wl (bf16), out_r = X@Wr + bl (f32). W from global (L2-hot).
__device__ __forceinline__ void tile_gemm32(
    const float* sX, const float* __restrict__ Wl, const float* __restrict__ bl,
    const float* __restrict__ Wr, int tile,
    __hip_bfloat16* __restrict__ PbOut, float* __restrict__ QOut) {
    int t = threadIdx.x;
    int dg = t & 15, ng = t >> 4;   // ng in 0..15; rows ng and ng+16
    float accL[2][4], accR[2][4];
#pragma unroll
    for (int i = 0; i < 2; i++)
#pragma unroll
        for (int j = 0; j < 4; j++) { accL[i][j] = 0.f; accR[i][j] = 0.f; }
#pragma unroll 4
    for (int k = 0; k < 64; k++) {
        float4 wl = ((const float4*)Wl)[k * 16 + dg];
        float4 wr = ((const float4*)Wr)[k * 16 + dg];
#pragma unroll
        for (int i = 0; i < 2; i++) {
            float xv = sX[(ng + i * 16) * XPAD + k];
            accL[i][0] = fmaf(xv, wl.x, accL[i][0]);
            accL[i][1] = fmaf(xv, wl.y, accL[i][1]);
            accL[i][2] = fmaf(xv, wl.z, accL[i][2]);
            accL[i][3] = fmaf(xv, wl.w, accL[i][3]);
            accR[i][0] = fmaf(xv, wr.x, accR[i][0]);
            accR[i][1] = fmaf(xv, wr.y, accR[i][1]);
            accR[i][2] = fmaf(xv, wr.z, accR[i][2]);
            accR[i][3] = fmaf(xv, wr.w, accR[i][3]);
        }
    }
    float4 blv = *(const float4*)&bl[dg * 4];
#pragma unroll
    for (int i = 0; i < 2; i++) {
        int node = tile + ng + i * 16;
        if (node < N_NODES) {
            union { ushort4 u; __hip_bfloat16 h[4]; } pk;
            pk.h[0] = __float2bfloat16(accL[i][0]);
            pk.h[1] = __float2bfloat16(accL[i][1]);
            pk.h[2] = __float2bfloat16(accL[i][2]);
            pk.h[3] = __float2bfloat16(accL[i][3]);
            *(ushort4*)&PbOut[(size_t)node * 64 + dg * 4] = pk.u;
            *(float4*)&QOut[(size_t)node * 64 + dg * 4] =
                make_float4(accR[i][0] + blv.x, accR[i][1] + blv.y,
                            accR[i][2] + blv.z, accR[i][3] + blv.w);
        }
    }
}

// ---------------- combo: bucket multi-split (blocks 0..EB) + layer-0 xform ----------------
__global__ __launch_bounds__(256) void k_combo(
    const int* __restrict__ esrc, const int* __restrict__ edst,
    int* __restrict__ cnt, int* __restrict__ ebuf,
    const int* __restrict__ ids, const float* __restrict__ emb,
    const float* __restrict__ Wl, const float* __restrict__ bl,
    const float* __restrict__ Wr,
    __hip_bfloat16* __restrict__ Pb, float* __restrict__ Qout) {
    __shared__ int smem[3 * NB_BKT > 32 * XPAD ? 3 * NB_BKT : 32 * XPAD];
    int t = threadIdx.x;
    if (blockIdx.x < EB_BLOCKS) {
        // ---- bsplit path ----
        int* h = smem;                 // NB_BKT
        int* bbase = h + NB_BKT;       // NB_BKT
        int* cur = bbase + NB_BKT;     // NB_BKT
        for (int i = t; i < NB_BKT; i += 256) { h[i] = 0; cur[i] = 0; }
        __syncthreads();
        int base = blockIdx.x * EB_CHUNK;
        int end = min(base + EB_CHUNK, N_EDGES);
        for (int i = base + t; i < end; i += 256)
            atomicAdd(&h[edst[i] >> BKT_SHIFT], 1);
        __syncthreads();
        for (int i = t; i < NB_BKT; i += 256)
            if (h[i]) bbase[i] = i * BKT_CAP + atomicAdd(&cnt[i], h[i]);
        __syncthreads();
        for (int i = base + t; i < end; i += 256) {
            int d = edst[i], s = esrc[i];
            int b = d >> BKT_SHIFT;
            int r = atomicAdd(&cur[b], 1);
            int slot = bbase[b] + r;
            if (slot < (b + 1) * BKT_CAP)          // defensive clamp
                ebuf[slot] = ((d & (BKT_NODES - 1)) << 16) | s;
        }
        return;
    }
    // ---- xform0 path ----
    float* sX = (float*)smem;
    int tile = (blockIdx.x - EB_BLOCKS) * 32;
    for (int i = t; i < 32 * 16; i += 256) {
        int r = i >> 4, c = i & 15;
        int node = tile + r;
        float4 v = make_float4(0.f, 0.f, 0.f, 0.f);
        if (node < N_NODES)
            v = ((const float4*)(emb + (size_t)ids[node] * 64))[c];
        *(float4*)&sX[r * XPAD + c * 4] = v;
    }
    __syncthreads();
    tile_gemm32(sX, Wl, bl, Wr, tile, Pb, Qout);
}

// ---------------- fused: LDS CSR + layer-0 aggregate + layer-1 xform ----------------
// Block = bucket = 32-node tile. H0 built in LDS, then single-pass GEMM (W from L2).
__global__ __launch_bounds__(256) void k_fused1(
    const int* __restrict__ cnt, const int* __restrict__ ebuf,
    const __hip_bfloat16* __restrict__ Pb0, const float* __restrict__ Wl,
    const float* __restrict__ bl, const float* __restrict__ Wr,
    __hip_bfloat16* __restrict__ Pb1, float* __restrict__ H) {
    __shared__ float sX[32 * XPAD];
    __shared__ unsigned short lcsr[BKT_CAP];
    __shared__ int nhist[BKT_NODES], sval[BKT_NODES], sexcl[BKT_NODES], ncur[BKT_NODES];
    int t = threadIdx.x;
    int tile = blockIdx.x * 32;
    build_local_csr(blockIdx.x, cnt, ebuf, lcsr, nhist, sval, sexcl, ncur);
    // phase (a): 1 node per eighth-wave, H0 = relu(mean+Q0) -> sX
    int ln = t >> 3, sl = t & 7;
    {
        int node = tile + ln;
        float m[8];
        agg_node8(sexcl[ln], sval[ln], sl, lcsr, Pb0, m);
        if (node < N_NODES) {
            size_t off = (size_t)node * 64 + sl * 8;
            float4 q0 = *(const float4*)&H[off];
            float4 q1 = *(const float4*)&H[off + 4];
            m[0] = fmaxf(m[0] + q0.x, 0.f);
            m[1] = fmaxf(m[1] + q0.y, 0.f);
            m[2] = fmaxf(m[2] + q0.z, 0.f);
            m[3] = fmaxf(m[3] + q0.w, 0.f);
            m[4] = fmaxf(m[4] + q1.x, 0.f);
            m[5] = fmaxf(m[5] + q1.y, 0.f);
            m[6] = fmaxf(m[6] + q1.z, 0.f);
            m[7] = fmaxf(m[7] + q1.w, 0.f);
        } else {
#pragma unroll
            for (int j = 0; j < 8; j++) m[j] = 0.f;
        }
        *(float4*)&sX[ln * XPAD + sl * 8] = make_float4(m[0], m[1], m[2], m[3]);
        *(float4*)&sX[ln * XPAD + sl * 8 + 4] = make_float4(m[4], m[5], m[6], m[7]);
    }
    __syncthreads();
    // phase (b): Pb1 = H0@Wl (bf16), H = H0@Wr + bl
    tile_gemm32(sX, Wl, bl, Wr, tile, Pb1, H);
}

// ---------------- layer-1 aggregate + pooling (block = bucket = 32 nodes) ----------------
__global__ __launch_bounds__(256) void k_agg2_pool(
    const int* __restrict__ cnt, const int* __restrict__ ebuf,
    const __hip_bfloat16* __restrict__ Pb, const float* __restrict__ H,
    const int* __restrict__ batch, float* __restrict__ psum) {
    __shared__ float acc[POOL_SPAN * 64];
    __shared__ unsigned short lcsr[BKT_CAP];
    __shared__ int nhist[BKT_NODES], sval[BKT_NODES], sexcl[BKT_NODES], ncur[BKT_NODES];
    int t = threadIdx.x;
    int nb = blockIdx.x * 32;
    for (int i = t; i < POOL_SPAN * 64; i += 256) acc[i] = 0.f;
    build_local_csr(blockIdx.x, cnt, ebuf, lcsr, nhist, sval, sexcl, ncur);
    int gmin = batch[nb];
    int ln = t >> 3, sl = t & 7;
    {
        int node = nb + ln;
        float m[8];
        agg_node8(sexcl[ln], sval[ln], sl, lcsr, Pb, m);
        if (node < N_NODES) {
            size_t off = (size_t)node * 64 + sl * 8;
            float4 q0 = *(const float4*)&H[off];
            float4 q1 = *(const float4*)&H[off + 4];
            m[0] = fmaxf(m[0] + q0.x, 0.f);
            m[1] = fmaxf(m[1] + q0.y, 0.f);
            m[2] = fmaxf(m[2] + q0.z, 0.f);
            m[3] = fmaxf(m[3] + q0.w, 0.f);
            m[4] = fmaxf(m[4] + q1.x, 0.f);
            m[5] = fmaxf(m[5] + q1.y, 0.f);
            m[6] = fmaxf(m[6] + q1.z, 0.f);
            m[7] = fmaxf(m[7] + q1.w, 0.f);
            int g = batch[node];
            int lg = g - gmin;
            if (lg < POOL_SPAN) {
#pragma unroll
                for (int j = 0; j < 8; j++)
                    atomicAdd(&acc[lg * 64 + sl * 8 + j], m[j]);
            } else {
#pragma unroll
                for (int j = 0; j < 8; j++)
                    atomicAdd(&psum[(size_t)g * 64 + sl * 8 + j], m[j]);
            }
        }
    }
    __syncthreads();
    int nlast = min(nb + 31, N_NODES - 1);
    int gspan = min(batch[nlast] - gmin + 1, POOL_SPAN);
    for (int i = t; i < gspan * 64; i += 256) {
        float v = acc[i];
        if (v != 0.f)
            atomicAdd(&psum[(size_t)(gmin + (i >> 6)) * 64 + (i & 63)], v);
    }
}

// ---------------- output projection ----------------
__device__ __forceinline__ int lower_bound_batch(const int* __restrict__ batch, int val) {
    int lo = 0, hi = N_NODES;
    while (lo < hi) {
        int mid = (lo + hi) >> 1;
        if (batch[mid] < val) lo = mid + 1; else hi = mid;
    }
    return lo;
}

__global__ __launch_bounds__(256) void k_out(
    const int* __restrict__ batch, const float* __restrict__ psum,
    const float* __restrict__ Wout, const float* __restrict__ bout,
    float* __restrict__ out) {
    int w = threadIdx.x >> 6, lane = threadIdx.x & 63;
    int g = blockIdx.x * 4 + w;
    if (g >= N_GRAPHS) return;
    int s0 = lower_bound_batch(batch, g);
    int s1 = lower_bound_batch(batch, g + 1);
    int cntg = s1 - s0;
    float inv = (cntg > 0) ? 1.0f / (float)cntg : 0.0f;
    float pooled = psum[(size_t)g * 64 + lane] * inv;
#pragma unroll
    for (int c = 0; c < N_CLASSES; c++) {
        float v = pooled * Wout[lane * N_CLASSES + c];
#pragma unroll
        for (int off = 32; off > 0; off >>= 1) v += __shfl_down(v, off, 64);
        if (lane == 0) out[(size_t)g * N_CLASSES + c] = v + bout[c];
    }
}

// ---------------- launch ----------------

extern "C" void kernel_launch(void* const* d_in, const int* in_sizes, int n_in,
                              void* d_out, int out_size, void* d_ws, size_t ws_size,
                              hipStream_t stream) {
    const int*   node_ids = (const int*)d_in[0];
    const int*   edge_idx = (const int*)d_in[1];   // [2, E] row-major
    const int*   batch    = (const int*)d_in[2];
    const float* emb      = (const float*)d_in[3];
    const float* Wl0      = (const float*)d_in[4];
    const float* bl0      = (const float*)d_in[5];
    const float* Wr0      = (const float*)d_in[6];
    const float* Wl1      = (const float*)d_in[7];
    const float* bl1      = (const float*)d_in[8];
    const float* Wr1      = (const float*)d_in[9];
    const float* Wout     = (const float*)d_in[10];
    const float* bout     = (const float*)d_in[11];
    float* out = (float*)d_out;

    const int* esrc = edge_idx;
    const int* edst = edge_idx + N_EDGES;

    // workspace layout
    __hip_bfloat16* Pb0 = (__hip_bfloat16*)d_ws;              // N*64 bf16
    __hip_bfloat16* Pb1 = Pb0 + (size_t)N_NODES * 64;         // N*64 bf16
    float* H = (float*)(Pb1 + (size_t)N_NODES * 64);          // N*64 f32
    int* ebuf = (int*)(H + (size_t)N_NODES * 64);             // NB*CAP ints (5.0 MB)
    int* cnt = ebuf + (size_t)NB_BKT * BKT_CAP;               // NB ints
    float* psum = (float*)(cnt + NB_BKT);                     // G*64 floats (contiguous w/ cnt)

    const int BLK = 256;

    // one memset zeroes bucket counters + pool accumulators (contiguous)
    hipMemsetAsync(cnt, 0, (NB_BKT + N_GRAPHS * 64) * sizeof(int), stream);

    // combo: bucket multi-split (98 blocks) + layer-0 xform (1563 blocks)
    k_combo<<<EB_BLOCKS + XFORM_BLOCKS, BLK, 0, stream>>>(
        esrc, edst, cnt, ebuf, node_ids, emb, Wl0, bl0, Wr0, Pb0, H);

    // fused layer-0 aggregate (LDS CSR) + layer-1 transform
    k_fused1<<<XFORM_BLOCKS, BLK, 0, stream>>>(cnt, ebuf, Pb0, Wl1, bl1, Wr1, Pb1, H);

    // layer-1 aggregate (LDS CSR) fused with graph pooling
    k_agg2_pool<<<NB_BKT, BLK, 0, stream>>>(cnt, ebuf, Pb1, H, batch, psum);

    // output projection
    k_out<<<(N_GRAPHS + 3) / 4, BLK, 0, stream>>>(batch, psum, Wout, bout, out);
}

// Round 15
// 216.647 us; speedup vs baseline: 1.1056x; 1.1056x over previous
//
#include <hip/hip_runtime.h>
#include <hip/hip_bf16.h>

#define N_NODES 50000
#define N_EDGES 800000
#define EMB 64
#define HID 64
#define N_CLASSES 10
#define N_GRAPHS 512

#define BKT_SHIFT 6
#define BKT_NODES 64
#define NB_BKT ((N_NODES + BKT_NODES - 1) / BKT_NODES)   // 782
#define BKT_CAP 1408     // mean 1024 + 12 sigma
#define EB_CHUNK 2048
#define EB_BLOCKS ((N_EDGES + EB_CHUNK - 1) / EB_CHUNK)  // 391
#define XFORM_BLOCKS ((N_NODES + 63) / 64)               // 782
#define XPAD 68
#define POOL_SPAN 66

// bf16 row accumulate: 8 bf16 dims (uint4) into fp32[8]
#define ACC8(vv, A)                                                            \
    do {                                                                       \
        A[0] += __uint_as_float((vv).x << 16);                                 \
        A[1] += __uint_as_float((vv).x & 0xFFFF0000u);                         \
        A[2] += __uint_as_float((vv).y << 16);                                 \
        A[3] += __uint_as_float((vv).y & 0xFFFF0000u);                         \
        A[4] += __uint_as_float((vv).z << 16);                                 \
        A[5] += __uint_as_float((vv).z & 0xFFFF0000u);                         \
        A[6] += __uint_as_float((vv).w << 16);                                 \
        A[7] += __uint_as_float((vv).w & 0xFFFF0000u);                         \
    } while (0)

// Build this bucket's CSR in LDS from its ebuf region. All 256 threads.
__device__ __forceinline__ void build_local_csr(
    int bucket, const int* __restrict__ cnt, const int* __restrict__ ebuf,
    unsigned short* lcsr, int* nhist, int* sval, int* sexcl, int* ncur) {
    int tid = threadIdx.x;
    int bs = bucket * BKT_CAP;
    int ne = min(cnt[bucket], BKT_CAP);   // defensive clamp
    if (tid < BKT_NODES) { nhist[tid] = 0; ncur[tid] = 0; }
    __syncthreads();
    for (int i = tid; i < ne; i += 256)
        atomicAdd(&nhist[ebuf[bs + i] >> 16], 1);
    __syncthreads();
    if (tid < BKT_NODES) sval[tid] = nhist[tid];
    __syncthreads();
    for (int off = 1; off < BKT_NODES; off <<= 1) {
        int t = 0;
        if (tid < BKT_NODES && tid >= off) t = nhist[tid - off];
        __syncthreads();
        if (tid < BKT_NODES) nhist[tid] += t;
        __syncthreads();
    }
    if (tid < BKT_NODES) sexcl[tid] = nhist[tid] - sval[tid];
    __syncthreads();
    for (int i = tid; i < ne; i += 256) {
        int p = ebuf[bs + i];
        int l = p >> 16;
        int r = atomicAdd(&ncur[l], 1);
        lcsr[sexcl[l] + r] = (unsigned short)(p & 0xFFFF);
    }
    __syncthreads();
}

// mean over neighbors (indices in LDS lcsr[s0..s0+deg)) for lane slot sl.
__device__ __forceinline__ void agg_node8(
    int s0, int deg, int sl,
    const unsigned short* lcsr,
    const __hip_bfloat16* __restrict__ Pb,
    float out[8]) {
    float a[4][8];
#pragma unroll
    for (int i = 0; i < 4; i++)
#pragma unroll
        for (int j = 0; j < 8; j++) a[i][j] = 0.f;
    int s1 = s0 + deg;
    for (int base = s0; base < s1; base += 8) {
        int c = min(8, s1 - base);
        if (c == 8) {
            int n0 = lcsr[base + 0];
            int n1 = lcsr[base + 1];
            int n2 = lcsr[base + 2];
            int n3 = lcsr[base + 3];
            int n4 = lcsr[base + 4];
            int n5 = lcsr[base + 5];
            int n6 = lcsr[base + 6];
            int n7 = lcsr[base + 7];
            uint4 v0 = ((const uint4*)(Pb + (size_t)n0 * 64))[sl];
            uint4 v1 = ((const uint4*)(Pb + (size_t)n1 * 64))[sl];
            uint4 v2 = ((const uint4*)(Pb + (size_t)n2 * 64))[sl];
            uint4 v3 = ((const uint4*)(Pb + (size_t)n3 * 64))[sl];
            uint4 v4 = ((const uint4*)(Pb + (size_t)n4 * 64))[sl];
            uint4 v5 = ((const uint4*)(Pb + (size_t)n5 * 64))[sl];
            uint4 v6 = ((const uint4*)(Pb + (size_t)n6 * 64))[sl];
            uint4 v7 = ((const uint4*)(Pb + (size_t)n7 * 64))[sl];
            ACC8(v0, a[0]); ACC8(v1, a[1]); ACC8(v2, a[2]); ACC8(v3, a[3]);
            ACC8(v4, a[0]); ACC8(v5, a[1]); ACC8(v6, a[2]); ACC8(v7, a[3]);
        } else {
            for (int j = 0; j < c; j++) {
                int n = lcsr[base + j];
                uint4 v = ((const uint4*)(Pb + (size_t)n * 64))[sl];
                ACC8(v, a[j & 3]);
            }
        }
    }
    float inv = (deg > 0) ? 1.0f / (float)deg : 0.0f;
#pragma unroll
    for (int j = 0; j < 8; j++)
        out[j] = (a[0][j] + a[1][j] + a[2][j] + a[3][j]) * inv;
}

// ---------------- combo: bucket multi-split (blocks 0..EB) + layer-0 xform ----------------
__global__ __launch_bounds__(256) void k_combo(
    const int* __restrict__ esrc, const int* __restrict__ edst,
    int* __restrict__ cnt, int* __restrict__ ebuf,
    const int* __restrict__ ids, const float* __restrict__ emb,
    const float* __restrict__ Wl, const float* __restrict__ bl,
    const float* __restrict__ Wr,
    __hip_bfloat16* __restrict__ Pb, float* __restrict__ Qout) {
    __shared__ float sW[64 * 64];
    __shared__ float sX[64 * XPAD];
    int t = threadIdx.x;
    if (blockIdx.x < EB_BLOCKS) {
        // ---- bsplit path: alias LDS as int scratch ----
        int* h = (int*)sW;                 // NB_BKT
        int* bbase = h + NB_BKT;           // NB_BKT
        int* cur = (int*)sX;               // NB_BKT
        for (int i = t; i < NB_BKT; i += 256) { h[i] = 0; cur[i] = 0; }
        __syncthreads();
        int base = blockIdx.x * EB_CHUNK;
        int end = min(base + EB_CHUNK, N_EDGES);
        for (int i = base + t; i < end; i += 256)
            atomicAdd(&h[edst[i] >> BKT_SHIFT], 1);
        __syncthreads();
        for (int i = t; i < NB_BKT; i += 256)
            if (h[i]) bbase[i] = i * BKT_CAP + atomicAdd(&cnt[i], h[i]);
        __syncthreads();
        for (int i = base + t; i < end; i += 256) {
            int d = edst[i], s = esrc[i];
            int b = d >> BKT_SHIFT;
            int r = atomicAdd(&cur[b], 1);
            int slot = bbase[b] + r;
            if (slot < (b + 1) * BKT_CAP)          // defensive clamp
                ebuf[slot] = ((d & (BKT_NODES - 1)) << 16) | s;
        }
        return;
    }
    // ---- xform0 path (two-pass W staging) ----
    int tile = (blockIdx.x - EB_BLOCKS) * 64;
    for (int i = t; i < 64 * 16; i += 256)
        ((float4*)sW)[i] = ((const float4*)Wl)[i];
    for (int i = t; i < 64 * 16; i += 256) {
        int r = i >> 4, c = i & 15;
        int node = tile + r;
        float4 v = make_float4(0.f, 0.f, 0.f, 0.f);
        if (node < N_NODES)
            v = ((const float4*)(emb + (size_t)ids[node] * 64))[c];
        *(float4*)&sX[r * XPAD + c * 4] = v;
    }
    __syncthreads();
    int dg = t & 15, ng = t >> 4;
    float acc[4][4];
#pragma unroll
    for (int i = 0; i < 4; i++)
#pragma unroll
        for (int j = 0; j < 4; j++) acc[i][j] = 0.f;
#pragma unroll 4
    for (int k = 0; k < 64; k++) {
        float4 w = *(const float4*)&sW[k * 64 + dg * 4];
#pragma unroll
        for (int i = 0; i < 4; i++) {
            float xv = sX[(ng + i * 16) * XPAD + k];
            acc[i][0] = fmaf(xv, w.x, acc[i][0]);
            acc[i][1] = fmaf(xv, w.y, acc[i][1]);
            acc[i][2] = fmaf(xv, w.z, acc[i][2]);
            acc[i][3] = fmaf(xv, w.w, acc[i][3]);
        }
    }
#pragma unroll
    for (int i = 0; i < 4; i++) {
        int node = tile + ng + i * 16;
        if (node < N_NODES) {
            union { ushort4 u; __hip_bfloat16 h[4]; } pk;
            pk.h[0] = __float2bfloat16(acc[i][0]);
            pk.h[1] = __float2bfloat16(acc[i][1]);
            pk.h[2] = __float2bfloat16(acc[i][2]);
            pk.h[3] = __float2bfloat16(acc[i][3]);
            *(ushort4*)&Pb[(size_t)node * 64 + dg * 4] = pk.u;
        }
    }
    __syncthreads();
    for (int i = t; i < 64 * 16; i += 256)
        ((float4*)sW)[i] = ((const float4*)Wr)[i];
    __syncthreads();
#pragma unroll
    for (int i = 0; i < 4; i++)
#pragma unroll
        for (int j = 0; j < 4; j++) acc[i][j] = 0.f;
#pragma unroll 4
    for (int k = 0; k < 64; k++) {
        float4 w = *(const float4*)&sW[k * 64 + dg * 4];
#pragma unroll
        for (int i = 0; i < 4; i++) {
            float xv = sX[(ng + i * 16) * XPAD + k];
            acc[i][0] = fmaf(xv, w.x, acc[i][0]);
            acc[i][1] = fmaf(xv, w.y, acc[i][1]);
            acc[i][2] = fmaf(xv, w.z, acc[i][2]);
            acc[i][3] = fmaf(xv, w.w, acc[i][3]);
        }
    }
    float4 blv = *(const float4*)&bl[dg * 4];
#pragma unroll
    for (int i = 0; i < 4; i++) {
        int node = tile + ng + i * 16;
        if (node < N_NODES)
            *(float4*)&Qout[(size_t)node * 64 + dg * 4] =
                make_float4(acc[i][0] + blv.x, acc[i][1] + blv.y,
                            acc[i][2] + blv.z, acc[i][3] + blv.w);
    }
}

// ---------------- fused: LDS CSR + layer-0 aggregate + layer-1 xform ----------------
// Block = bucket = 64-node tile. H0 built in LDS, then two-pass GEMM.
__global__ __launch_bounds__(256) void k_fused1(
    const int* __restrict__ cnt, const int* __restrict__ ebuf,
    const __hip_bfloat16* __restrict__ Pb0, const float* __restrict__ Wl,
    const float* __restrict__ bl, const float* __restrict__ Wr,
    __hip_bfloat16* __restrict__ Pb1, float* __restrict__ H) {
    __shared__ float sW[64 * 64];
    __shared__ float sX[64 * XPAD];
    __shared__ unsigned short lcsr[BKT_CAP];
    __shared__ int nhist[BKT_NODES], sval[BKT_NODES], sexcl[BKT_NODES], ncur[BKT_NODES];
    int t = threadIdx.x;
    int tile = blockIdx.x * 64;
    // Wl prefetch issues early; hides behind CSR build + gather
    for (int i = t; i < 64 * 16; i += 256)
        ((float4*)sW)[i] = ((const float4*)Wl)[i];
    build_local_csr(blockIdx.x, cnt, ebuf, lcsr, nhist, sval, sexcl, ncur);
    // phase (a): aggregate 2 nodes per eighth-wave, H0 = relu(mean+Q0) -> sX
    int grp = t >> 3, sl = t & 7;
    for (int nn = 0; nn < 2; nn++) {
        int ln = grp * 2 + nn;
        int node = tile + ln;
        float m[8];
        agg_node8(sexcl[ln], sval[ln], sl, lcsr, Pb0, m);
        if (node < N_NODES) {
            size_t off = (size_t)node * 64 + sl * 8;
            float4 q0 = *(const float4*)&H[off];
            float4 q1 = *(const float4*)&H[off + 4];
            m[0] = fmaxf(m[0] + q0.x, 0.f);
            m[1] = fmaxf(m[1] + q0.y, 0.f);
            m[2] = fmaxf(m[2] + q0.z, 0.f);
            m[3] = fmaxf(m[3] + q0.w, 0.f);
            m[4] = fmaxf(m[4] + q1.x, 0.f);
            m[5] = fmaxf(m[5] + q1.y, 0.f);
            m[6] = fmaxf(m[6] + q1.z, 0.f);
            m[7] = fmaxf(m[7] + q1.w, 0.f);
        } else {
#pragma unroll
            for (int j = 0; j < 8; j++) m[j] = 0.f;
        }
        *(float4*)&sX[ln * XPAD + sl * 8] = make_float4(m[0], m[1], m[2], m[3]);
        *(float4*)&sX[ln * XPAD + sl * 8 + 4] = make_float4(m[4], m[5], m[6], m[7]);
    }
    __syncthreads();
    // phase (b1): Pb1 = H0 @ Wl
    int dg = t & 15, ng = t >> 4;
    float acc[4][4];
#pragma unroll
    for (int i = 0; i < 4; i++)
#pragma unroll
        for (int j = 0; j < 4; j++) acc[i][j] = 0.f;
#pragma unroll 4
    for (int k = 0; k < 64; k++) {
        float4 w = *(const float4*)&sW[k * 64 + dg * 4];
#pragma unroll
        for (int i = 0; i < 4; i++) {
            float xv = sX[(ng + i * 16) * XPAD + k];
            acc[i][0] = fmaf(xv, w.x, acc[i][0]);
            acc[i][1] = fmaf(xv, w.y, acc[i][1]);
            acc[i][2] = fmaf(xv, w.z, acc[i][2]);
            acc[i][3] = fmaf(xv, w.w, acc[i][3]);
        }
    }
#pragma unroll
    for (int i = 0; i < 4; i++) {
        int node = tile + ng + i * 16;
        if (node < N_NODES) {
            union { ushort4 u; __hip_bfloat16 h[4]; } pk;
            pk.h[0] = __float2bfloat16(acc[i][0]);
            pk.h[1] = __float2bfloat16(acc[i][1]);
            pk.h[2] = __float2bfloat16(acc[i][2]);
            pk.h[3] = __float2bfloat16(acc[i][3]);
            *(ushort4*)&Pb1[(size_t)node * 64 + dg * 4] = pk.u;
        }
    }
    __syncthreads();
    for (int i = t; i < 64 * 16; i += 256)
        ((float4*)sW)[i] = ((const float4*)Wr)[i];
    __syncthreads();
    // phase (b2): H = Q1 = H0 @ Wr + bl
#pragma unroll
    for (int i = 0; i < 4; i++)
#pragma unroll
        for (int j = 0; j < 4; j++) acc[i][j] = 0.f;
#pragma unroll 4
    for (int k = 0; k < 64; k++) {
        float4 w = *(const float4*)&sW[k * 64 + dg * 4];
#pragma unroll
        for (int i = 0; i < 4; i++) {
            float xv = sX[(ng + i * 16) * XPAD + k];
            acc[i][0] = fmaf(xv, w.x, acc[i][0]);
            acc[i][1] = fmaf(xv, w.y, acc[i][1]);
            acc[i][2] = fmaf(xv, w.z, acc[i][2]);
            acc[i][3] = fmaf(xv, w.w, acc[i][3]);
        }
    }
    float4 blv = *(const float4*)&bl[dg * 4];
#pragma unroll
    for (int i = 0; i < 4; i++) {
        int node = tile + ng + i * 16;
        if (node < N_NODES)
            *(float4*)&H[(size_t)node * 64 + dg * 4] =
                make_float4(acc[i][0] + blv.x, acc[i][1] + blv.y,
                            acc[i][2] + blv.z, acc[i][3] + blv.w);
    }
}

// ---------------- layer-1 aggregate + pooling (block = bucket = 64 nodes) ----------------
__global__ __launch_bounds__(256) void k_agg2_pool(
    const int* __restrict__ cnt, const int* __restrict__ ebuf,
    const __hip_bfloat16* __restrict__ Pb, const float* __restrict__ H,
    const int* __restrict__ batch, float* __restrict__ psum) {
    __shared__ float acc[POOL_SPAN * 64];
    __shared__ unsigned short lcsr[BKT_CAP];
    __shared__ int nhist[BKT_NODES], sval[BKT_NODES], sexcl[BKT_NODES], ncur[BKT_NODES];
    int t = threadIdx.x;
    int nb = blockIdx.x * 64;
    for (int i = t; i < POOL_SPAN * 64; i += 256) acc[i] = 0.f;
    build_local_csr(blockIdx.x, cnt, ebuf, lcsr, nhist, sval, sexcl, ncur);
    int gmin = batch[nb];
    int grp = t >> 3, sl = t & 7;
    for (int nn = 0; nn < 2; nn++) {
        int ln = grp * 2 + nn;
        int node = nb + ln;
        float m[8];
        agg_node8(sexcl[ln], sval[ln], sl, lcsr, Pb, m);
        if (node < N_NODES) {
            size_t off = (size_t)node * 64 + sl * 8;
            float4 q0 = *(const float4*)&H[off];
            float4 q1 = *(const float4*)&H[off + 4];
            m[0] = fmaxf(m[0] + q0.x, 0.f);
            m[1] = fmaxf(m[1] + q0.y, 0.f);
            m[2] = fmaxf(m[2] + q0.z, 0.f);
            m[3] = fmaxf(m[3] + q0.w, 0.f);
            m[4] = fmaxf(m[4] + q1.x, 0.f);
            m[5] = fmaxf(m[5] + q1.y, 0.f);
            m[6] = fmaxf(m[6] + q1.z, 0.f);
            m[7] = fmaxf(m[7] + q1.w, 0.f);
            int g = batch[node];
            int lg = g - gmin;
            if (lg < POOL_SPAN) {
#pragma unroll
                for (int j = 0; j < 8; j++)
                    atomicAdd(&acc[lg * 64 + sl * 8 + j], m[j]);
            } else {
#pragma unroll
                for (int j = 0; j < 8; j++)
                    atomicAdd(&psum[(size_t)g * 64 + sl * 8 + j], m[j]);
            }
        }
    }
    __syncthreads();
    int nlast = min(nb + 63, N_NODES - 1);
    int gspan = min(batch[nlast] - gmin + 1, POOL_SPAN);
    for (int i = t; i < gspan * 64; i += 256) {
        float v = acc[i];
        if (v != 0.f)
            atomicAdd(&psum[(size_t)(gmin + (i >> 6)) * 64 + (i & 63)], v);
    }
}

// ---------------- output projection ----------------
__device__ __forceinline__ int lower_bound_batch(const int* __restrict__ batch, int val) {
    int lo = 0, hi = N_NODES;
    while (lo < hi) {
        int mid = (lo + hi) >> 1;
        if (batch[mid] < val) lo = mid + 1; else hi = mid;
    }
    return lo;
}

__global__ __launch_bounds__(256) void k_out(
    const int* __restrict__ batch, const float* __restrict__ psum,
    const float* __restrict__ Wout, const float* __restrict__ bout,
    float* __restrict__ out) {
    int w = threadIdx.x >> 6, lane = threadIdx.x & 63;
    int g = blockIdx.x * 4 + w;
    if (g >= N_GRAPHS) return;
    int s0 = lower_bound_batch(batch, g);
    int s1 = lower_bound_batch(batch, g + 1);
    int cntg = s1 - s0;
    float inv = (cntg > 0) ? 1.0f / (float)cntg : 0.0f;
    float pooled = psum[(size_t)g * 64 + lane] * inv;
#pragma unroll
    for (int c = 0; c < N_CLASSES; c++) {
        float v = pooled * Wout[lane * N_CLASSES + c];
#pragma unroll
        for (int off = 32; off > 0; off >>= 1) v += __shfl_down(v, off, 64);
        if (lane == 0) out[(size_t)g * N_CLASSES + c] = v + bout[c];
    }
}

// ---------------- launch ----------------

extern "C" void kernel_launch(void* const* d_in, const int* in_sizes, int n_in,
                              void* d_out, int out_size, void* d_ws, size_t ws_size,
                              hipStream_t stream) {
    const int*   node_ids = (const int*)d_in[0];
    const int*   edge_idx = (const int*)d_in[1];   // [2, E] row-major
    const int*   batch    = (const int*)d_in[2];
    const float* emb      = (const float*)d_in[3];
    const float* Wl0      = (const float*)d_in[4];
    const float* bl0      = (const float*)d_in[5];
    const float* Wr0      = (const float*)d_in[6];
    const float* Wl1      = (const float*)d_in[7];
    const float* bl1      = (const float*)d_in[8];
    const float* Wr1      = (const float*)d_in[9];
    const float* Wout     = (const float*)d_in[10];
    const float* bout     = (const float*)d_in[11];
    float* out = (float*)d_out;

    const int* esrc = edge_idx;
    const int* edst = edge_idx + N_EDGES;

    // workspace layout
    __hip_bfloat16* Pb0 = (__hip_bfloat16*)d_ws;              // N*64 bf16
    __hip_bfloat16* Pb1 = Pb0 + (size_t)N_NODES * 64;         // N*64 bf16
    float* H = (float*)(Pb1 + (size_t)N_NODES * 64);          // N*64 f32
    int* ebuf = (int*)(H + (size_t)N_NODES * 64);             // NB*CAP ints
    int* cnt = ebuf + (size_t)NB_BKT * BKT_CAP;               // NB ints
    float* psum = (float*)(cnt + NB_BKT);                     // G*64 floats (contiguous w/ cnt)

    const int BLK = 256;

    // one memset zeroes bucket counters + pool accumulators (contiguous)
    hipMemsetAsync(cnt, 0, (NB_BKT + N_GRAPHS * 64) * sizeof(int), stream);

    // combo: bucket multi-split (391 blocks) + layer-0 xform (782 blocks)
    k_combo<<<EB_BLOCKS + XFORM_BLOCKS, BLK, 0, stream>>>(
        esrc, edst, cnt, ebuf, node_ids, emb, Wl0, bl0, Wr0, Pb0, H);

    // fused layer-0 aggregate (LDS CSR) + layer-1 transform
    k_fused1<<<XFORM_BLOCKS, BLK, 0, stream>>>(cnt, ebuf, Pb0, Wl1, bl1, Wr1, Pb1, H);

    // layer-1 aggregate (LDS CSR) fused with graph pooling
    k_agg2_pool<<<NB_BKT, BLK, 0, stream>>>(cnt, ebuf, Pb1, H, batch, psum);

    // output projection
    k_out<<<(N_GRAPHS + 3) / 4, BLK, 0, stream>>>(batch, psum, Wout, bout, out);
}